// Round 1
// baseline (1409.908 us; speedup 1.0000x reference)
//
#include <hip/hip_runtime.h>
#include <stdint.h>

#define DD 128

// ---------- bf16 helpers (self-contained, RTNE) ----------
__device__ __forceinline__ unsigned short f2bf(float f) {
  unsigned u = __float_as_uint(f);
  unsigned r = u + 0x7fffu + ((u >> 16) & 1u);
  return (unsigned short)(r >> 16);
}
__device__ __forceinline__ unsigned pack2(float a, float b) {
  return (unsigned)f2bf(a) | ((unsigned)f2bf(b) << 16);
}
__device__ __forceinline__ float2 unpack2(unsigned p) {
  float2 r;
  r.x = __uint_as_float(p << 16);
  r.y = __uint_as_float(p & 0xffff0000u);
  return r;
}

// ---------- CSR build ----------
__global__ __launch_bounds__(256) void k_deg(const int* __restrict__ dst, int* deg, int e) {
  int i = blockIdx.x * 256 + threadIdx.x;
  if (i < e) atomicAdd(&deg[dst[i]], 1);
}

__global__ __launch_bounds__(1024) void k_scan(const int* __restrict__ deg, int* __restrict__ rowstart,
                                               int* __restrict__ cursor, float* __restrict__ invdeg, int n) {
  __shared__ int part[1024];
  int t = threadIdx.x;
  int chunk = (n + 1023) >> 10;
  int lo = t * chunk;
  int hi = lo + chunk; if (hi > n) hi = n;
  int s = 0;
  for (int i = lo; i < hi; ++i) s += deg[i];
  part[t] = s;
  __syncthreads();
  for (int off = 1; off < 1024; off <<= 1) {
    int v = part[t];
    int add = (t >= off) ? part[t - off] : 0;
    __syncthreads();
    part[t] = v + add;
    __syncthreads();
  }
  int run = (t == 0) ? 0 : part[t - 1];
  for (int i = lo; i < hi; ++i) {
    int d = deg[i];
    rowstart[i] = run;
    cursor[i] = run;
    invdeg[i] = 1.0f / (float)(d > 1 ? d : 1);
    run += d;
  }
  if (t == 1023) rowstart[n] = run;
}

__global__ __launch_bounds__(256) void k_fill(const int* __restrict__ src, const int* __restrict__ dst,
                                              int* cursor, int* __restrict__ esrc, int e) {
  int i = blockIdx.x * 256 + threadIdx.x;
  if (i < e) {
    int p = atomicAdd(&cursor[dst[i]], 1);
    esrc[p] = src[i];
  }
}

// ---------- mean aggregation: one wave per dst row ----------
__global__ __launch_bounds__(256) void k_aggr(const float* __restrict__ h, const int* __restrict__ rowstart,
                                              const int* __restrict__ esrc, const float* __restrict__ invdeg,
                                              float* __restrict__ out, int n) {
  int wave = threadIdx.x >> 6, lane = threadIdx.x & 63;
  int r = blockIdx.x * 4 + wave;
  if (r >= n) return;
  int ru = __builtin_amdgcn_readfirstlane(r);
  int beg = rowstart[ru], end = rowstart[ru + 1];
  float inv = invdeg[ru];
  float a0 = 0.f, a1 = 0.f;
  for (int j = beg; j < end; ++j) {
    int s = __builtin_amdgcn_readfirstlane(esrc[j]);
    const float2 v = *(const float2*)&h[(size_t)s * DD + lane * 2];
    a0 += v.x; a1 += v.y;
  }
  float2 o; o.x = a0 * inv; o.y = a1 * inv;
  *(float2*)&out[(size_t)r * DD + lane * 2] = o;
}

// ---------- GEMM: out = act(in @ W + b), one wave per row, bf16 W in LDS ----------
// ACT: 0 none, 1 tanh, 2 silu
template <int ACT>
__global__ __launch_bounds__(256) void k_fc(const float* __restrict__ in, const float* __restrict__ W,
                                            const float* __restrict__ b, float* __restrict__ out, int n) {
  __shared__ unsigned sW[128 * 64];  // [k][col-pair], 32 KB
  for (int i = threadIdx.x; i < 128 * 64; i += 256) {
    float2 w = *(const float2*)&W[2 * i];
    sW[i] = pack2(w.x, w.y);
  }
  int wave = threadIdx.x >> 6, lane = threadIdx.x & 63;
  int c0 = lane * 2;
  float bb0 = b[c0], bb1 = b[c0 + 1];
  __syncthreads();
  int r = blockIdx.x * 4 + wave;
  if (r >= n) return;
  int ru = __builtin_amdgcn_readfirstlane(r);
  const float* row = in + (size_t)ru * DD;
  float acc0 = bb0, acc1 = bb1;
#pragma unroll 8
  for (int k = 0; k < 128; ++k) {
    float a = row[k];
    float2 w = unpack2(sW[k * 64 + lane]);
    acc0 = fmaf(a, w.x, acc0);
    acc1 = fmaf(a, w.y, acc1);
  }
  if (ACT == 1) { acc0 = tanhf(acc0); acc1 = tanhf(acc1); }
  else if (ACT == 2) { acc0 = acc0 / (1.f + __expf(-acc0)); acc1 = acc1 / (1.f + __expf(-acc1)); }
  float2 o; o.x = acc0; o.y = acc1;
  *(float2*)&out[(size_t)r * DD + c0] = o;
}

// ---------- SAGE layer: out = act(h @ Ws + bs + ng @ Wn) ----------
template <int ACT>
__global__ __launch_bounds__(256) void k_sage(const float* __restrict__ h, const float* __restrict__ ng,
                                              const float* __restrict__ Ws, const float* __restrict__ Wn,
                                              const float* __restrict__ bs, float* __restrict__ out, int n) {
  __shared__ unsigned sW[256 * 64];  // 64 KB: first half Ws, second half Wn
  for (int i = threadIdx.x; i < 128 * 64; i += 256) {
    float2 ws = *(const float2*)&Ws[2 * i];
    float2 wn = *(const float2*)&Wn[2 * i];
    sW[i] = pack2(ws.x, ws.y);
    sW[128 * 64 + i] = pack2(wn.x, wn.y);
  }
  int wave = threadIdx.x >> 6, lane = threadIdx.x & 63;
  int c0 = lane * 2;
  float bb0 = bs[c0], bb1 = bs[c0 + 1];
  __syncthreads();
  int r = blockIdx.x * 4 + wave;
  if (r >= n) return;
  int ru = __builtin_amdgcn_readfirstlane(r);
  const float* rowh = h + (size_t)ru * DD;
  const float* rowg = ng + (size_t)ru * DD;
  float acc0 = bb0, acc1 = bb1;
#pragma unroll 8
  for (int k = 0; k < 128; ++k) {
    float a = rowh[k];
    float2 w = unpack2(sW[k * 64 + lane]);
    acc0 = fmaf(a, w.x, acc0);
    acc1 = fmaf(a, w.y, acc1);
  }
#pragma unroll 8
  for (int k = 0; k < 128; ++k) {
    float a = rowg[k];
    float2 w = unpack2(sW[(128 + k) * 64 + lane]);
    acc0 = fmaf(a, w.x, acc0);
    acc1 = fmaf(a, w.y, acc1);
  }
  if (ACT == 1) { acc0 = tanhf(acc0); acc1 = tanhf(acc1); }
  else if (ACT == 2) { acc0 = acc0 / (1.f + __expf(-acc0)); acc1 = acc1 / (1.f + __expf(-acc1)); }
  float2 o; o.x = acc0; o.y = acc1;
  *(float2*)&out[(size_t)r * DD + c0] = o;
}

extern "C" void kernel_launch(void* const* d_in, const int* in_sizes, int n_in,
                              void* d_out, int out_size, void* d_ws, size_t ws_size,
                              hipStream_t stream) {
  const float* h_in = (const float*)d_in[0];
  const int* src    = (const int*)d_in[1];
  const int* dst    = (const int*)d_in[2];
  const float* W1   = (const float*)d_in[3];
  const float* b1   = (const float*)d_in[4];
  const float* W2   = (const float*)d_in[5];
  const float* b2   = (const float*)d_in[6];
  const float* Wself  = (const float*)d_in[7];
  const float* bself  = (const float*)d_in[8];
  const float* Wneigh = (const float*)d_in[9];
  const int N = in_sizes[0] / DD;
  const int E = in_sizes[1];
  float* out = (float*)d_out;

  char* ws = (char*)d_ws;
  size_t off = 0;
  auto alloc = [&](size_t bytes) -> char* {
    char* p = ws + off;
    off = (off + bytes + 255) & ~(size_t)255;
    return p;
  };
  float* bufA   = (float*)alloc((size_t)N * DD * 4);
  float* neigh  = (float*)alloc((size_t)N * DD * 4);
  int* esrc     = (int*)alloc((size_t)E * 4);
  int* degi     = (int*)alloc((size_t)N * 4);
  int* rowstart = (int*)alloc((size_t)(N + 1) * 4);
  int* cursor   = (int*)alloc((size_t)N * 4);
  float* invdeg = (float*)alloc((size_t)N * 4);

  hipMemsetAsync(degi, 0, (size_t)N * 4, stream);
  const int eb = (E + 255) / 256;
  k_deg<<<eb, 256, 0, stream>>>(dst, degi, E);
  k_scan<<<1, 1024, 0, stream>>>(degi, rowstart, cursor, invdeg, N);
  k_fill<<<eb, 256, 0, stream>>>(src, dst, cursor, esrc, E);

  const int rb = (N + 3) / 4;
  // fc_in: t = tanh(h@W1+b1) -> out ; h0 = t@W2+b2 -> bufA
  k_fc<1><<<rb, 256, 0, stream>>>(h_in, W1, b1, out, N);
  k_fc<0><<<rb, 256, 0, stream>>>(out, W2, b2, bufA, N);

  const float* cur = bufA;
  float* nxt = out;
  for (int l = 0; l < 3; ++l) {
    k_aggr<<<rb, 256, 0, stream>>>(cur, rowstart, esrc, invdeg, neigh, N);
    const float* Ws = Wself + (size_t)l * DD * DD;
    const float* Wn = Wneigh + (size_t)l * DD * DD;
    const float* bs = bself + (size_t)l * DD;
    if (l < 2) k_sage<2><<<rb, 256, 0, stream>>>(cur, neigh, Ws, Wn, bs, nxt, N);
    else       k_sage<1><<<rb, 256, 0, stream>>>(cur, neigh, Ws, Wn, bs, nxt, N);
    const float* tmp = cur;
    cur = (const float*)nxt;
    nxt = (float*)tmp;
  }
}

// Round 2
// 491.097 us; speedup vs baseline: 2.8709x; 2.8709x over previous
//
#include <hip/hip_runtime.h>
#include <stdint.h>

#define DD 128

typedef __attribute__((ext_vector_type(8))) short short8;
typedef __attribute__((ext_vector_type(4))) float float4v;

// ---------- bf16 helpers (RTNE) ----------
__device__ __forceinline__ unsigned short f2bf(float f) {
  unsigned u = __float_as_uint(f);
  unsigned r = u + 0x7fffu + ((u >> 16) & 1u);
  return (unsigned short)(r >> 16);
}
__device__ __forceinline__ unsigned pack2(float a, float b) {
  return (unsigned)f2bf(a) | ((unsigned)f2bf(b) << 16);
}
__device__ __forceinline__ float2 unpack2(unsigned p) {
  float2 r;
  r.x = __uint_as_float(p << 16);
  r.y = __uint_as_float(p & 0xffff0000u);
  return r;
}

// ---------- CSR build ----------
__global__ __launch_bounds__(256) void k_deg(const int* __restrict__ dst, int* deg, int e) {
  int i = blockIdx.x * 256 + threadIdx.x;
  if (i < e) atomicAdd(&deg[dst[i]], 1);
}

__global__ __launch_bounds__(1024) void k_scan(const int* __restrict__ deg, int* __restrict__ rowstart,
                                               int* __restrict__ cursor, float* __restrict__ invdeg, int n) {
  __shared__ int part[1024];
  int t = threadIdx.x;
  int chunk = (n + 1023) >> 10;
  int lo = t * chunk;
  int hi = lo + chunk; if (hi > n) hi = n;
  int s = 0;
  for (int i = lo; i < hi; ++i) s += deg[i];
  part[t] = s;
  __syncthreads();
  for (int off = 1; off < 1024; off <<= 1) {
    int v = part[t];
    int add = (t >= off) ? part[t - off] : 0;
    __syncthreads();
    part[t] = v + add;
    __syncthreads();
  }
  int run = (t == 0) ? 0 : part[t - 1];
  for (int i = lo; i < hi; ++i) {
    int d = deg[i];
    rowstart[i] = run;
    cursor[i] = run;
    invdeg[i] = 1.0f / (float)(d > 1 ? d : 1);
    run += d;
  }
  if (t == 1023) rowstart[n] = run;
}

__global__ __launch_bounds__(256) void k_fill(const int* __restrict__ src, const int* __restrict__ dst,
                                              int* cursor, int* __restrict__ esrc, int e) {
  int i = blockIdx.x * 256 + threadIdx.x;
  if (i < e) {
    int p = atomicAdd(&cursor[dst[i]], 1);
    esrc[p] = src[i];
  }
}

// ---------- weight prep: fp32 [k][n] -> bf16 fragment-major for mfma_16x16x32 B-operand ----------
// frag layout per matrix: uint32 idx = ((c*4 + t)*64 + lane)*4 + p
//   n = c*16 + (lane&15), k = t*32 + (lane>>4)*8 + 2p ; value = pack2(W[k][n], W[k+1][n])
__global__ __launch_bounds__(256) void k_prep_w(const float* __restrict__ W1, const float* __restrict__ W2,
                                                const float* __restrict__ Wself, const float* __restrict__ Wneigh,
                                                unsigned* __restrict__ wfrag) {
  int gid = blockIdx.x * 256 + threadIdx.x;  // 0 .. 65536
  int m = gid >> 13;
  int r = gid & 8191;
  int p = r & 3;
  int lane = (r >> 2) & 63;
  int t = (r >> 8) & 3;
  int c = r >> 10;
  const float* W;
  if (m == 0) W = W1;
  else if (m == 1) W = W2;
  else if (m < 5) W = Wself + (size_t)(m - 2) * DD * DD;
  else W = Wneigh + (size_t)(m - 5) * DD * DD;
  int n = c * 16 + (lane & 15);
  int k = t * 32 + (lane >> 4) * 8 + 2 * p;
  wfrag[gid] = pack2(W[(size_t)k * DD + n], W[(size_t)(k + 1) * DD + n]);
}

// ---------- mean aggregation (bf16 in/out, fp32 accum): one wave per dst row ----------
__global__ __launch_bounds__(256) void k_aggr(const unsigned* __restrict__ h, const int* __restrict__ rowstart,
                                              const int* __restrict__ esrc, const float* __restrict__ invdeg,
                                              unsigned* __restrict__ out, int n) {
  int wave = threadIdx.x >> 6, lane = threadIdx.x & 63;
  int r = blockIdx.x * 4 + wave;
  if (r >= n) return;
  int ru = __builtin_amdgcn_readfirstlane(r);
  int beg = rowstart[ru], end = rowstart[ru + 1];
  float inv = invdeg[ru];
  float a0 = 0.f, a1 = 0.f;
  int j = beg;
  for (; j + 4 <= end; j += 4) {
    int s0 = esrc[j], s1 = esrc[j + 1], s2 = esrc[j + 2], s3 = esrc[j + 3];
    unsigned v0 = h[(size_t)s0 * 64 + lane];
    unsigned v1 = h[(size_t)s1 * 64 + lane];
    unsigned v2 = h[(size_t)s2 * 64 + lane];
    unsigned v3 = h[(size_t)s3 * 64 + lane];
    float2 f0 = unpack2(v0), f1 = unpack2(v1), f2 = unpack2(v2), f3 = unpack2(v3);
    a0 += (f0.x + f1.x) + (f2.x + f3.x);
    a1 += (f0.y + f1.y) + (f2.y + f3.y);
  }
  for (; j < end; ++j) {
    float2 f = unpack2(h[(size_t)esrc[j] * 64 + lane]);
    a0 += f.x; a1 += f.y;
  }
  out[(size_t)r * 64 + lane] = pack2(a0 * inv, a1 * inv);
}

// ---------- MFMA GEMM: out = act(in @ W + b), 64 rows/block, 16 rows/wave ----------
// ACT: 0 none, 1 tanh, 2 silu
template <int ACT, bool INF32, bool OUTF32>
__global__ __launch_bounds__(256) void k_fc(const void* __restrict__ in, const uint4* __restrict__ wfrag,
                                            const float* __restrict__ bias, void* __restrict__ out, int n) {
  __shared__ uint4 sW[2048];  // 32 KB fragment-major weights
  int tid = threadIdx.x;
  for (int i = tid; i < 2048; i += 256) sW[i] = wfrag[i];
  int wave = tid >> 6, lane = tid & 63;
  int quad = lane >> 4, nn = lane & 15;
  int r0 = (blockIdx.x * 4 + wave) * 16;
  int rr = r0 + nn; if (rr >= n) rr = n - 1;
  short8 a[4];
  if (INF32) {
    const float* X = (const float*)in + (size_t)rr * DD;
#pragma unroll
    for (int t = 0; t < 4; ++t) {
      int k0 = t * 32 + quad * 8;
      float4 f0 = *(const float4*)&X[k0];
      float4 f1 = *(const float4*)&X[k0 + 4];
      uint4 u;
      u.x = pack2(f0.x, f0.y); u.y = pack2(f0.z, f0.w);
      u.z = pack2(f1.x, f1.y); u.w = pack2(f1.z, f1.w);
      a[t] = __builtin_bit_cast(short8, u);
    }
  } else {
    const uint4* X = (const uint4*)in + (size_t)rr * (DD / 8);
#pragma unroll
    for (int t = 0; t < 4; ++t) {
      a[t] = __builtin_bit_cast(short8, X[t * 4 + quad]);
    }
  }
  float4v acc[8];
#pragma unroll
  for (int c = 0; c < 8; ++c) acc[c] = (float4v){0.f, 0.f, 0.f, 0.f};
  __syncthreads();
#pragma unroll
  for (int c = 0; c < 8; ++c) {
#pragma unroll
    for (int t = 0; t < 4; ++t) {
      short8 b = __builtin_bit_cast(short8, sW[(c * 4 + t) * 64 + lane]);
      acc[c] = __builtin_amdgcn_mfma_f32_16x16x32_bf16(a[t], b, acc[c], 0, 0, 0);
    }
  }
#pragma unroll
  for (int c = 0; c < 8; ++c) {
    float bcol = bias[c * 16 + nn];
#pragma unroll
    for (int g = 0; g < 4; ++g) {
      int row = r0 + quad * 4 + g;
      if (row < n) {
        float v = acc[c][g] + bcol;
        if (ACT == 1) v = tanhf(v);
        else if (ACT == 2) v = v / (1.f + __expf(-v));
        if (OUTF32) ((float*)out)[(size_t)row * DD + c * 16 + nn] = v;
        else ((unsigned short*)out)[(size_t)row * DD + c * 16 + nn] = f2bf(v);
      }
    }
  }
}

// ---------- MFMA SAGE layer: out = act(X @ Ws + bs + G @ Wn) ----------
template <int ACT, bool OUTF32>
__global__ __launch_bounds__(256) void k_sage(const uint4* __restrict__ X, const uint4* __restrict__ G,
                                              const uint4* __restrict__ wsF, const uint4* __restrict__ wnF,
                                              const float* __restrict__ bias, void* __restrict__ out, int n) {
  __shared__ uint4 sW[4096];  // 64 KB: [0..2047]=Ws frags, [2048..4095]=Wn frags
  int tid = threadIdx.x;
  for (int i = tid; i < 2048; i += 256) {
    sW[i] = wsF[i];
    sW[2048 + i] = wnF[i];
  }
  int wave = tid >> 6, lane = tid & 63;
  int quad = lane >> 4, nn = lane & 15;
  int r0 = (blockIdx.x * 4 + wave) * 16;
  int rr = r0 + nn; if (rr >= n) rr = n - 1;
  short8 a[4], g[4];
  {
    const uint4* Xr = X + (size_t)rr * (DD / 8);
    const uint4* Gr = G + (size_t)rr * (DD / 8);
#pragma unroll
    for (int t = 0; t < 4; ++t) {
      a[t] = __builtin_bit_cast(short8, Xr[t * 4 + quad]);
      g[t] = __builtin_bit_cast(short8, Gr[t * 4 + quad]);
    }
  }
  float4v acc[8];
#pragma unroll
  for (int c = 0; c < 8; ++c) acc[c] = (float4v){0.f, 0.f, 0.f, 0.f};
  __syncthreads();
#pragma unroll
  for (int c = 0; c < 8; ++c) {
#pragma unroll
    for (int t = 0; t < 4; ++t) {
      short8 b = __builtin_bit_cast(short8, sW[(c * 4 + t) * 64 + lane]);
      acc[c] = __builtin_amdgcn_mfma_f32_16x16x32_bf16(a[t], b, acc[c], 0, 0, 0);
    }
#pragma unroll
    for (int t = 0; t < 4; ++t) {
      short8 b = __builtin_bit_cast(short8, sW[2048 + (c * 4 + t) * 64 + lane]);
      acc[c] = __builtin_amdgcn_mfma_f32_16x16x32_bf16(g[t], b, acc[c], 0, 0, 0);
    }
  }
#pragma unroll
  for (int c = 0; c < 8; ++c) {
    float bcol = bias[c * 16 + nn];
#pragma unroll
    for (int gg = 0; gg < 4; ++gg) {
      int row = r0 + quad * 4 + gg;
      if (row < n) {
        float v = acc[c][gg] + bcol;
        if (ACT == 1) v = tanhf(v);
        else if (ACT == 2) v = v / (1.f + __expf(-v));
        if (OUTF32) ((float*)out)[(size_t)row * DD + c * 16 + nn] = v;
        else ((unsigned short*)out)[(size_t)row * DD + c * 16 + nn] = f2bf(v);
      }
    }
  }
}

extern "C" void kernel_launch(void* const* d_in, const int* in_sizes, int n_in,
                              void* d_out, int out_size, void* d_ws, size_t ws_size,
                              hipStream_t stream) {
  const float* h_in = (const float*)d_in[0];
  const int* src    = (const int*)d_in[1];
  const int* dst    = (const int*)d_in[2];
  const float* W1   = (const float*)d_in[3];
  const float* b1   = (const float*)d_in[4];
  const float* W2   = (const float*)d_in[5];
  const float* b2   = (const float*)d_in[6];
  const float* Wself  = (const float*)d_in[7];
  const float* bself  = (const float*)d_in[8];
  const float* Wneigh = (const float*)d_in[9];
  const int N = in_sizes[0] / DD;
  const int E = in_sizes[1];
  float* out = (float*)d_out;

  char* ws = (char*)d_ws;
  size_t off = 0;
  auto alloc = [&](size_t bytes) -> char* {
    char* p = ws + off;
    off = (off + bytes + 255) & ~(size_t)255;
    return p;
  };
  unsigned* wfrag = (unsigned*)alloc(8 * 32768);               // 8 matrices, frag-major bf16
  unsigned* actA  = (unsigned*)alloc((size_t)N * 64 * 4);      // bf16 [N][128]
  unsigned* actB  = (unsigned*)alloc((size_t)N * 64 * 4);
  unsigned* neigh = (unsigned*)alloc((size_t)N * 64 * 4);
  int* esrc     = (int*)alloc((size_t)E * 4);
  int* degi     = (int*)alloc((size_t)N * 4);
  int* rowstart = (int*)alloc((size_t)(N + 1) * 4);
  int* cursor   = (int*)alloc((size_t)N * 4);
  float* invdeg = (float*)alloc((size_t)N * 4);

  hipMemsetAsync(degi, 0, (size_t)N * 4, stream);
  const int eb = (E + 255) / 256;
  k_deg<<<eb, 256, 0, stream>>>(dst, degi, E);
  k_scan<<<1, 1024, 0, stream>>>(degi, rowstart, cursor, invdeg, N);
  k_fill<<<eb, 256, 0, stream>>>(src, dst, cursor, esrc, E);
  k_prep_w<<<256, 256, 0, stream>>>(W1, W2, Wself, Wneigh, wfrag);

  const int gb = (N + 63) / 64;
  const int ab = (N + 3) / 4;
  const uint4* wf = (const uint4*)wfrag;  // 2048 uint4 per matrix

  // fc_in: tanh(h@W1+b1) -> actA ; actA@W2+b2 -> actB
  k_fc<1, true,  false><<<gb, 256, 0, stream>>>(h_in, wf + 0 * 2048, b1, actA, N);
  k_fc<0, false, false><<<gb, 256, 0, stream>>>(actA, wf + 1 * 2048, b2, actB, N);

  const unsigned* cur = actB;
  unsigned* nxt = actA;
  for (int l = 0; l < 3; ++l) {
    k_aggr<<<ab, 256, 0, stream>>>(cur, rowstart, esrc, invdeg, neigh, N);
    const uint4* wsF = wf + (size_t)(2 + l) * 2048;
    const uint4* wnF = wf + (size_t)(5 + l) * 2048;
    const float* bs = bself + (size_t)l * DD;
    if (l < 2) {
      k_sage<2, false><<<gb, 256, 0, stream>>>((const uint4*)cur, (const uint4*)neigh, wsF, wnF, bs, nxt, N);
      const unsigned* tmp = cur;
      cur = nxt;
      nxt = (unsigned*)tmp;
    } else {
      k_sage<1, true><<<gb, 256, 0, stream>>>((const uint4*)cur, (const uint4*)neigh, wsF, wnF, bs, out, N);
    }
  }
}

// Round 3
// 363.210 us; speedup vs baseline: 3.8818x; 1.3521x over previous
//
#include <hip/hip_runtime.h>
#include <stdint.h>

#define DD 128

typedef __attribute__((ext_vector_type(8))) short short8;
typedef __attribute__((ext_vector_type(4))) float float4v;

// ---------- bf16 helpers (RTNE) ----------
__device__ __forceinline__ unsigned short f2bf(float f) {
  unsigned u = __float_as_uint(f);
  unsigned r = u + 0x7fffu + ((u >> 16) & 1u);
  return (unsigned short)(r >> 16);
}
__device__ __forceinline__ unsigned pack2(float a, float b) {
  return (unsigned)f2bf(a) | ((unsigned)f2bf(b) << 16);
}
__device__ __forceinline__ float2 unpack2(unsigned p) {
  float2 r;
  r.x = __uint_as_float(p << 16);
  r.y = __uint_as_float(p & 0xffff0000u);
  return r;
}

// ---------- CSR build ----------
__global__ __launch_bounds__(256) void k_deg(const int* __restrict__ dst, int* deg, int e) {
  int i = blockIdx.x * 256 + threadIdx.x;
  if (i < e) atomicAdd(&deg[dst[i]], 1);
}

// phase 1: per-block inclusive scan of 1024 elements (coalesced), emit block sums
__global__ __launch_bounds__(1024) void k_scan1(const int* __restrict__ deg, int* __restrict__ incl,
                                                int* __restrict__ bsum, int n) {
  __shared__ int sh[1024];
  int t = threadIdx.x;
  int i = blockIdx.x * 1024 + t;
  int v = (i < n) ? deg[i] : 0;
  sh[t] = v;
  __syncthreads();
#pragma unroll
  for (int off = 1; off < 1024; off <<= 1) {
    int add = (t >= off) ? sh[t - off] : 0;
    __syncthreads();
    sh[t] += add;
    __syncthreads();
  }
  if (i < n) incl[i] = sh[t];
  if (t == 1023) bsum[blockIdx.x] = sh[1023];
}

// phase 2: single-wave exclusive scan of block sums (nb <= 64)
__global__ __launch_bounds__(64) void k_scan2(const int* __restrict__ bsum, int* __restrict__ boff, int nb) {
  int t = threadIdx.x;
  int v = (t < nb) ? bsum[t] : 0;
#pragma unroll
  for (int off = 1; off < 64; off <<= 1) {
    int u = __shfl_up(v, off);
    if ((t & 63) >= off) v += u;
  }
  if (t < nb) boff[t] = v - ((t < nb) ? bsum[t] : 0);  // exclusive
  if (t == 63) boff[nb] = v;                           // total (lane 63 holds full sum)
}

// phase 3: emit rowstart/cursor/invdeg (coalesced)
__global__ __launch_bounds__(1024) void k_scan3(const int* __restrict__ deg, const int* __restrict__ incl,
                                                const int* __restrict__ boff, int* __restrict__ rowstart,
                                                int* __restrict__ cursor, float* __restrict__ invdeg, int n) {
  int i = blockIdx.x * 1024 + threadIdx.x;
  if (i >= n) return;
  int d = deg[i];
  int excl = boff[blockIdx.x] + incl[i] - d;
  rowstart[i] = excl;
  cursor[i] = excl;
  invdeg[i] = 1.0f / (float)(d > 1 ? d : 1);
  if (i == n - 1) rowstart[n] = excl + d;
}

__global__ __launch_bounds__(256) void k_fill(const int* __restrict__ src, const int* __restrict__ dst,
                                              int* cursor, int* __restrict__ esrc, int e) {
  int i = blockIdx.x * 256 + threadIdx.x;
  if (i < e) {
    int p = atomicAdd(&cursor[dst[i]], 1);
    esrc[p] = src[i];
  }
}

// ---------- weight prep: fp32 [k][n] -> bf16 fragment-major for mfma_16x16x32 B-operand ----------
__global__ __launch_bounds__(256) void k_prep_w(const float* __restrict__ W1, const float* __restrict__ W2,
                                                const float* __restrict__ Wself, const float* __restrict__ Wneigh,
                                                unsigned* __restrict__ wfrag) {
  int gid = blockIdx.x * 256 + threadIdx.x;  // 0 .. 65536
  int m = gid >> 13;
  int r = gid & 8191;
  int p = r & 3;
  int lane = (r >> 2) & 63;
  int t = (r >> 8) & 3;
  int c = r >> 10;
  const float* W;
  if (m == 0) W = W1;
  else if (m == 1) W = W2;
  else if (m < 5) W = Wself + (size_t)(m - 2) * DD * DD;
  else W = Wneigh + (size_t)(m - 5) * DD * DD;
  int n = c * 16 + (lane & 15);
  int k = t * 32 + (lane >> 4) * 8 + 2 * p;
  wfrag[gid] = pack2(W[(size_t)k * DD + n], W[(size_t)(k + 1) * DD + n]);
}

// ---------- mean aggregation (bf16 in/out, fp32 accum): one wave per dst row ----------
__global__ __launch_bounds__(256) void k_aggr(const unsigned* __restrict__ h, const int* __restrict__ rowstart,
                                              const int* __restrict__ esrc, const float* __restrict__ invdeg,
                                              unsigned* __restrict__ out, int n) {
  int wave = threadIdx.x >> 6, lane = threadIdx.x & 63;
  int r = blockIdx.x * 4 + wave;
  if (r >= n) return;
  int ru = __builtin_amdgcn_readfirstlane(r);
  int beg = rowstart[ru], end = rowstart[ru + 1];
  float inv = invdeg[ru];
  float a0 = 0.f, a1 = 0.f;
  int j = beg;
  for (; j + 4 <= end; j += 4) {
    int s0 = esrc[j], s1 = esrc[j + 1], s2 = esrc[j + 2], s3 = esrc[j + 3];
    unsigned v0 = h[(size_t)s0 * 64 + lane];
    unsigned v1 = h[(size_t)s1 * 64 + lane];
    unsigned v2 = h[(size_t)s2 * 64 + lane];
    unsigned v3 = h[(size_t)s3 * 64 + lane];
    float2 f0 = unpack2(v0), f1 = unpack2(v1), f2 = unpack2(v2), f3 = unpack2(v3);
    a0 += (f0.x + f1.x) + (f2.x + f3.x);
    a1 += (f0.y + f1.y) + (f2.y + f3.y);
  }
  for (; j < end; ++j) {
    float2 f = unpack2(h[(size_t)esrc[j] * 64 + lane]);
    a0 += f.x; a1 += f.y;
  }
  out[(size_t)r * 64 + lane] = pack2(a0 * inv, a1 * inv);
}

// ---------- MFMA GEMM: out = act(in @ W + b), 64 rows/block, 16 rows/wave ----------
// ACT: 0 none, 1 tanh, 2 silu
template <int ACT, bool INF32, bool OUTF32>
__global__ __launch_bounds__(256) void k_fc(const void* __restrict__ in, const uint4* __restrict__ wfrag,
                                            const float* __restrict__ bias, void* __restrict__ out, int n) {
  __shared__ uint4 sW[2048];  // 32 KB fragment-major weights
  int tid = threadIdx.x;
  for (int i = tid; i < 2048; i += 256) sW[i] = wfrag[i];
  int wave = tid >> 6, lane = tid & 63;
  int quad = lane >> 4, nn = lane & 15;
  int r0 = (blockIdx.x * 4 + wave) * 16;
  int rr = r0 + nn; if (rr >= n) rr = n - 1;
  short8 a[4];
  if (INF32) {
    const float* X = (const float*)in + (size_t)rr * DD;
#pragma unroll
    for (int t = 0; t < 4; ++t) {
      int k0 = t * 32 + quad * 8;
      float4 f0 = *(const float4*)&X[k0];
      float4 f1 = *(const float4*)&X[k0 + 4];
      uint4 u;
      u.x = pack2(f0.x, f0.y); u.y = pack2(f0.z, f0.w);
      u.z = pack2(f1.x, f1.y); u.w = pack2(f1.z, f1.w);
      a[t] = __builtin_bit_cast(short8, u);
    }
  } else {
    const uint4* X = (const uint4*)in + (size_t)rr * (DD / 8);
#pragma unroll
    for (int t = 0; t < 4; ++t) {
      a[t] = __builtin_bit_cast(short8, X[t * 4 + quad]);
    }
  }
  float4v acc[8];
#pragma unroll
  for (int c = 0; c < 8; ++c) acc[c] = (float4v){0.f, 0.f, 0.f, 0.f};
  __syncthreads();
#pragma unroll
  for (int c = 0; c < 8; ++c) {
#pragma unroll
    for (int t = 0; t < 4; ++t) {
      short8 b = __builtin_bit_cast(short8, sW[(c * 4 + t) * 64 + lane]);
      acc[c] = __builtin_amdgcn_mfma_f32_16x16x32_bf16(a[t], b, acc[c], 0, 0, 0);
    }
  }
#pragma unroll
  for (int c = 0; c < 8; ++c) {
    float bcol = bias[c * 16 + nn];
#pragma unroll
    for (int g = 0; g < 4; ++g) {
      int row = r0 + quad * 4 + g;
      if (row < n) {
        float v = acc[c][g] + bcol;
        if (ACT == 1) v = tanhf(v);
        else if (ACT == 2) v = v / (1.f + __expf(-v));
        if (OUTF32) ((float*)out)[(size_t)row * DD + c * 16 + nn] = v;
        else ((unsigned short*)out)[(size_t)row * DD + c * 16 + nn] = f2bf(v);
      }
    }
  }
}

// ---------- MFMA SAGE layer: out = act(X @ Ws + bs + G @ Wn) ----------
template <int ACT, bool OUTF32>
__global__ __launch_bounds__(256) void k_sage(const uint4* __restrict__ X, const uint4* __restrict__ G,
                                              const uint4* __restrict__ wsF, const uint4* __restrict__ wnF,
                                              const float* __restrict__ bias, void* __restrict__ out, int n) {
  __shared__ uint4 sW[4096];  // 64 KB: [0..2047]=Ws frags, [2048..4095]=Wn frags
  int tid = threadIdx.x;
  for (int i = tid; i < 2048; i += 256) {
    sW[i] = wsF[i];
    sW[2048 + i] = wnF[i];
  }
  int wave = tid >> 6, lane = tid & 63;
  int quad = lane >> 4, nn = lane & 15;
  int r0 = (blockIdx.x * 4 + wave) * 16;
  int rr = r0 + nn; if (rr >= n) rr = n - 1;
  short8 a[4], g[4];
  {
    const uint4* Xr = X + (size_t)rr * (DD / 8);
    const uint4* Gr = G + (size_t)rr * (DD / 8);
#pragma unroll
    for (int t = 0; t < 4; ++t) {
      a[t] = __builtin_bit_cast(short8, Xr[t * 4 + quad]);
      g[t] = __builtin_bit_cast(short8, Gr[t * 4 + quad]);
    }
  }
  float4v acc[8];
#pragma unroll
  for (int c = 0; c < 8; ++c) acc[c] = (float4v){0.f, 0.f, 0.f, 0.f};
  __syncthreads();
#pragma unroll
  for (int c = 0; c < 8; ++c) {
#pragma unroll
    for (int t = 0; t < 4; ++t) {
      short8 b = __builtin_bit_cast(short8, sW[(c * 4 + t) * 64 + lane]);
      acc[c] = __builtin_amdgcn_mfma_f32_16x16x32_bf16(a[t], b, acc[c], 0, 0, 0);
    }
#pragma unroll
    for (int t = 0; t < 4; ++t) {
      short8 b = __builtin_bit_cast(short8, sW[2048 + (c * 4 + t) * 64 + lane]);
      acc[c] = __builtin_amdgcn_mfma_f32_16x16x32_bf16(g[t], b, acc[c], 0, 0, 0);
    }
  }
#pragma unroll
  for (int c = 0; c < 8; ++c) {
    float bcol = bias[c * 16 + nn];
#pragma unroll
    for (int gg = 0; gg < 4; ++gg) {
      int row = r0 + quad * 4 + gg;
      if (row < n) {
        float v = acc[c][gg] + bcol;
        if (ACT == 1) v = tanhf(v);
        else if (ACT == 2) v = v / (1.f + __expf(-v));
        if (OUTF32) ((float*)out)[(size_t)row * DD + c * 16 + nn] = v;
        else ((unsigned short*)out)[(size_t)row * DD + c * 16 + nn] = f2bf(v);
      }
    }
  }
}

extern "C" void kernel_launch(void* const* d_in, const int* in_sizes, int n_in,
                              void* d_out, int out_size, void* d_ws, size_t ws_size,
                              hipStream_t stream) {
  const float* h_in = (const float*)d_in[0];
  const int* src    = (const int*)d_in[1];
  const int* dst    = (const int*)d_in[2];
  const float* W1   = (const float*)d_in[3];
  const float* b1   = (const float*)d_in[4];
  const float* W2   = (const float*)d_in[5];
  const float* b2   = (const float*)d_in[6];
  const float* Wself  = (const float*)d_in[7];
  const float* bself  = (const float*)d_in[8];
  const float* Wneigh = (const float*)d_in[9];
  const int N = in_sizes[0] / DD;
  const int E = in_sizes[1];
  float* out = (float*)d_out;

  char* ws = (char*)d_ws;
  size_t off = 0;
  auto alloc = [&](size_t bytes) -> char* {
    char* p = ws + off;
    off = (off + bytes + 255) & ~(size_t)255;
    return p;
  };
  unsigned* wfrag = (unsigned*)alloc(8 * 32768);               // 8 matrices, frag-major bf16
  unsigned* actA  = (unsigned*)alloc((size_t)N * 64 * 4);      // bf16 [N][128]
  unsigned* actB  = (unsigned*)alloc((size_t)N * 64 * 4);
  unsigned* neigh = (unsigned*)alloc((size_t)N * 64 * 4);
  int* esrc     = (int*)alloc((size_t)E * 4);
  int* degi     = (int*)alloc((size_t)N * 4);
  int* rowstart = (int*)alloc((size_t)(N + 1) * 4);
  int* cursor   = (int*)alloc((size_t)N * 4);
  float* invdeg = (float*)alloc((size_t)N * 4);
  int* incl     = (int*)alloc((size_t)N * 4);
  int* bsum     = (int*)alloc(65 * 4);
  int* boff     = (int*)alloc(65 * 4);

  hipMemsetAsync(degi, 0, (size_t)N * 4, stream);
  const int eb = (E + 255) / 256;
  const int nb = (N + 1023) / 1024;  // 49 <= 64
  k_deg<<<eb, 256, 0, stream>>>(dst, degi, E);
  k_scan1<<<nb, 1024, 0, stream>>>(degi, incl, bsum, N);
  k_scan2<<<1, 64, 0, stream>>>(bsum, boff, nb);
  k_scan3<<<nb, 1024, 0, stream>>>(degi, incl, boff, rowstart, cursor, invdeg, N);
  k_fill<<<eb, 256, 0, stream>>>(src, dst, cursor, esrc, E);
  k_prep_w<<<256, 256, 0, stream>>>(W1, W2, Wself, Wneigh, wfrag);

  const int gb = (N + 63) / 64;
  const int ab = (N + 3) / 4;
  const uint4* wf = (const uint4*)wfrag;  // 2048 uint4 per matrix

  // fc_in: tanh(h@W1+b1) -> actA ; actA@W2+b2 -> actB
  k_fc<1, true,  false><<<gb, 256, 0, stream>>>(h_in, wf + 0 * 2048, b1, actA, N);
  k_fc<0, false, false><<<gb, 256, 0, stream>>>(actA, wf + 1 * 2048, b2, actB, N);

  const unsigned* cur = actB;
  unsigned* nxt = actA;
  for (int l = 0; l < 3; ++l) {
    k_aggr<<<ab, 256, 0, stream>>>(cur, rowstart, esrc, invdeg, neigh, N);
    const uint4* wsF = wf + (size_t)(2 + l) * 2048;
    const uint4* wnF = wf + (size_t)(5 + l) * 2048;
    const float* bs = bself + (size_t)l * DD;
    if (l < 2) {
      k_sage<2, false><<<gb, 256, 0, stream>>>((const uint4*)cur, (const uint4*)neigh, wsF, wnF, bs, nxt, N);
      const unsigned* tmp = cur;
      cur = nxt;
      nxt = (unsigned*)tmp;
    } else {
      k_sage<1, true><<<gb, 256, 0, stream>>>((const uint4*)cur, (const uint4*)neigh, wsF, wnF, bs, out, N);
    }
  }
}